// Round 9
// baseline (429.258 us; speedup 1.0000x reference)
//
#include <hip/hip_runtime.h>

#define B_ 16
#define N_ 1024
#define C_ 768
#define E_ 8
#define H_ 192

typedef __bf16 bf16x8 __attribute__((ext_vector_type(8)));
typedef float  f32x4  __attribute__((ext_vector_type(4)));

// ---------------------------------------------------------------------------
// Kernel 1: prep. (a) pack fc1_w/fc2_w to bf16 in MFMA-B-fragment order:
//   pw1[e][kb=c/32][n=h][c%32], pw2[e][kb=h/32][n=c][h%32]
// (b) transpose gate_w to gwT[d][j][c] (f32); rows 0..7 clean, 8..15 noise.
// ---------------------------------------------------------------------------
__global__ __launch_bounds__(256) void prep_kernel(
    const float* __restrict__ w1, const float* __restrict__ w2,
    const float* __restrict__ gw,
    __bf16* __restrict__ pw1, __bf16* __restrict__ pw2,
    float* __restrict__ gwT) {
  int idx = blockIdx.x * 256 + threadIdx.x;            // float4 index
  const int nW4 = (E_ * H_ * C_) / 4;                  // 294912
  if (idx >= nW4) return;
  int flat = idx * 4;
  int e = flat / (H_ * C_);
  int r = flat - e * (H_ * C_);

  // w1: [e][h][c] -> pw1
  {
    float4 a = *(const float4*)(w1 + (size_t)flat);
    int n = r / C_;           // h
    int c = r - n * C_;       // c, %4==0
    size_t o = ((size_t)(e * 24 + (c >> 5)) * 192 + n) * 32 + (c & 31);
    pw1[o + 0] = (__bf16)a.x; pw1[o + 1] = (__bf16)a.y;
    pw1[o + 2] = (__bf16)a.z; pw1[o + 3] = (__bf16)a.w;
  }
  // w2: [e][c][h] -> pw2
  {
    float4 a = *(const float4*)(w2 + (size_t)flat);
    int n = r / H_;           // c index 0..767
    int h = r - n * H_;       // 0..191, %4==0
    size_t o = ((size_t)(e * 6 + (h >> 5)) * 768 + n) * 32 + (h & 31);
    pw2[o + 0] = (__bf16)a.x; pw2[o + 1] = (__bf16)a.y;
    pw2[o + 2] = (__bf16)a.z; pw2[o + 3] = (__bf16)a.w;
  }
  // gwT: [d][c][16] -> [d][j][c]
  if (idx < (4 * 16 * C_) / 4) {
    int f = idx * 4;
    int d = f / (16 * C_);
    int rr = f - d * (16 * C_);
    int j = rr / C_;
    int c = rr - j * C_;      // %4==0
    const float* src = gw + (size_t)d * C_ * 16 + j;
    float4 v;
    v.x = src[(size_t)(c + 0) * 16]; v.y = src[(size_t)(c + 1) * 16];
    v.z = src[(size_t)(c + 2) * 16]; v.w = src[(size_t)(c + 3) * 16];
    *(float4*)(gwT + (size_t)f) = v;
  }
}

// ---------------------------------------------------------------------------
// Kernel 2: gating. Grid = B*64 blocks, 16 tokens each, 256 thr (broadcast
// mapping: 16 lanes share one gwT row -> 4 addrs/wave). Per-block partial
// expert sums -> psums[bid][8].
// ---------------------------------------------------------------------------
__global__ __launch_bounds__(256, 3) void gate_kernel(
    const float* __restrict__ x, const int* __restrict__ task_ids,
    const float* __restrict__ eps, const float* __restrict__ gwT,
    float* __restrict__ psums) {
  const int b = blockIdx.x >> 6;
  const int token0 = (blockIdx.x & 63) * 16;
  const int tid = threadIdx.x;

  __shared__ __align__(16) float xt[16][772];   // pad 4: 2-way (free) reads
  __shared__ float sc[16][16];
  __shared__ float red[16][8];

  const float* xbase = x + ((size_t)b * N_ + token0) * C_;
  for (int it = 0; it < 12; ++it) {
    int chunk = it * 256 + tid;                 // 0..3071
    int row = chunk / 192;
    int col4 = chunk - row * 192;
    float4 v = *(const float4*)(xbase + (size_t)row * C_ + col4 * 4);
    *(float4*)&xt[row][col4 * 4] = v;
  }
  __syncthreads();

  const int t = tid & 15;
  const int j = tid >> 4;                       // 16 lanes share one j
  const int task = task_ids[b];
  const float* wrow = gwT + ((size_t)task * 16 + j) * C_;
  float acc = 0.0f;
#pragma unroll 4
  for (int c = 0; c < C_; c += 4) {
    float4 xv = *(const float4*)&xt[t][c];
    float4 wv = *(const float4*)(wrow + c);
    acc += xv.x * wv.x + xv.y * wv.y + xv.z * wv.z + xv.w * wv.w;
  }
  sc[t][j] = acc;
  __syncthreads();
  if (j < 8) {
    float clean = sc[t][j];
    float raw = sc[t][j + 8];
    float sp = (raw > 20.0f) ? raw : log1pf(expf(raw));
    red[t][j] = clean +
        eps[((size_t)b * N_ + token0 + t) * E_ + j] * (sp + 0.01f);
  }
  __syncthreads();
  if (tid < 8) {
    float s = 0.0f;
#pragma unroll
    for (int tt = 0; tt < 16; ++tt) s += red[tt][tid];
    psums[(size_t)blockIdx.x * 8 + tid] = s;
  }
}

// ---------------------------------------------------------------------------
// Kernel 3: top-2 + 2-expert adapter, LDS-STAGED WEIGHT STREAM.
// Grid = 256 blocks x 512 thr (8 waves = 2 wm x 4 wn, M=32/wave), 64
// tokens/block, XCD-pinned. Both GEMMs consume uniform 12,288B weight
// tiles: G1 = 24 kb-tiles of pw1; G2 = 4 col-slices x 6 kb-tiles of pw2.
// Flat 96-step stream (2 experts x 48), triple-buffered LDS staging,
// reg-staged (global->reg->LDS) with loads issued 3 STEPS AHEAD of their
// ds_write -> vmcnt satisfied by elapsed compute, no serialized L2 waits
// (the diagnosed 67us pathology: compiler reuses few VGPRs for direct
// loads -> load/waitcnt/use chains). One barrier/step; buffers race-free
// by %3 rotation. Tiles XOR-swizzled at 8B granularity (u^=row&7), read
// as 2x ds_read_b64 -> 2-way banks (free). Weights dedup'd across wm.
// ---------------------------------------------------------------------------
#define XS_OFF   0                            // bf16 xs[64][776] = 99328
#define HS_OFF   99328                        // bf16 hs[64][200] = 25600
#define STG_OFF  (99328 + 25600)              // 3 x 12288 = 36864
#define SMC_OFF  (STG_OFF + 36864)            // 32
#define SMEM_EXPERT (SMC_OFF + 32)            // 161824 B

__global__ __launch_bounds__(512, 2) void expert_kernel(
    const float* __restrict__ x, const __bf16* __restrict__ pw1,
    const __bf16* __restrict__ pw2, const float* __restrict__ fc1_b,
    const float* __restrict__ fc2_b, const float* __restrict__ psums,
    float* __restrict__ out) {
  const int bid = blockIdx.x;
  const int sxc = bid >> 3;                    // 0..31 within an XCD
  const int b = (bid & 7) * 2 + (sxc >> 4);    // 2 consecutive samples / XCD
  const int token0 = (sxc & 15) * 64;
  const int tid = threadIdx.x;
  const int wave = tid >> 6;
  const int wm = wave >> 2;                    // token half (0/1)
  const int wn = wave & 3;                     // N slice (0..3)
  const int lane = tid & 63;
  const int ln = lane & 15;
  const int qq = lane >> 4;                    // 0..3
  const int q8 = qq * 8;
  const int q4 = qq * 4;
  const int arow = wm * 32;

  extern __shared__ char smem[];
  __bf16 (*xs)[776] = reinterpret_cast<__bf16(*)[776]>(smem + XS_OFF);
  __bf16 (*hs)[200] = reinterpret_cast<__bf16(*)[200]>(smem + HS_OFF);
  char* stg = smem + STG_OFF;
  float* smc = reinterpret_cast<float*>(smem + SMC_OFF);

  // ---- per-sample gate sums: wave e reduces 64 tile-partials --------------
  {
    float v = psums[(((size_t)b << 6) | lane) * 8 + wave];
#pragma unroll
    for (int off = 32; off; off >>= 1) v += __shfl_down(v, off);
    if (lane == 0) smc[wave] = v;
  }
  __syncthreads();

  // top-2 (tie rule matches lax.top_k: strict >, stable)
  int e_idx[2]; float gate_v[2];
  {
    float best = -INFINITY, best2 = -INFINITY;
    int i1 = 0, i2 = 0;
#pragma unroll
    for (int e = 0; e < E_; ++e) {
      float v = smc[e];
      if (v > best) { best2 = best; i2 = i1; best = v; i1 = e; }
      else if (v > best2) { best2 = v; i2 = e; }
    }
    float d = best - best2;
    float st = d / (d + 1e-6f);
    float et = expf(st);
    e_idx[0] = i1; gate_v[0] = et / (et + 1.0f);
    e_idx[1] = i2; gate_v[1] = 1.0f / (et + 1.0f);
  }

  // weight stream sources (147456 bf16 elems per expert in BOTH pw1, pw2)
  const char* wsrc[2][2];
  wsrc[0][0] = (const char*)(pw1 + (size_t)e_idx[0] * 147456);
  wsrc[0][1] = (const char*)(pw2 + (size_t)e_idx[0] * 147456);
  wsrc[1][0] = (const char*)(pw1 + (size_t)e_idx[1] * 147456);
  wsrc[1][1] = (const char*)(pw2 + (size_t)e_idx[1] * 147456);

  // tile s (0..95): ex=s/48, t=s%48. t<24: G1 kb=t (12288B each).
  // t>=24: G2 slice=(t-24)/6, kb=(t-24)%6 at kb*49152 + slice*12288.
#define TSRC(s) \
  (((s) % 48) < 24 \
     ? wsrc[(s) / 48][0] + (size_t)((s) % 48) * 12288 \
     : wsrc[(s) / 48][1] + (size_t)(((s) % 48 - 24) % 6) * 49152 \
                         + (size_t)(((s) % 48 - 24) / 6) * 12288)

  // issue: 768 16B-chunks/tile over 512 thr (threads<256 take a 2nd chunk)
#define ISSUE(s, d0, d1)                                          \
  if ((s) < 96) {                                                 \
    const char* gsrc_ = TSRC(s);                                  \
    d0 = *(const uint4*)(gsrc_ + (size_t)tid * 16);               \
    if (tid < 256) d1 = *(const uint4*)(gsrc_ + 8192 + (size_t)tid * 16); \
  }

  // swizzled write: chunk c -> row r=c>>2, part p=c&3; 8B units u=2p,2p+1
  // land at u^(r&7). (waits vmcnt for d0/d1's loads -- issued 3 steps ago)
#define WCHUNK(bufp, c, d)                                        \
  {                                                               \
    int r_ = (c) >> 2, p_ = (c) & 3, sw_ = r_ & 7;                \
    char* rp_ = (bufp) + r_ * 64;                                 \
    *(uint2*)(rp_ + (((p_ << 1)    ) ^ sw_) * 8) = make_uint2((d).x, (d).y); \
    *(uint2*)(rp_ + (((p_ << 1) | 1) ^ sw_) * 8) = make_uint2((d).z, (d).w); \
  }
#define WTILE(s, d0, d1)                                          \
  if ((s) < 96) {                                                 \
    char* buf_ = stg + ((s) % 3) * 12288;                         \
    WCHUNK(buf_, tid, d0);                                        \
    if (tid < 256) WCHUNK(buf_, 512 + tid, d1);                   \
  }

  // swizzled b-frag read: row n, k-quarter qq -> two ds_read_b64
#define RFRAG(dst, bufp, n)                                       \
  {                                                               \
    const char* rp_ = (bufp) + (n) * 64;                          \
    int sw_ = (n) & 7;                                            \
    uint2 lo_ = *(const uint2*)(rp_ + (((qq << 1)    ) ^ sw_) * 8); \
    uint2 hi_ = *(const uint2*)(rp_ + (((qq << 1) | 1) ^ sw_) * 8); \
    union { uint v[4]; bf16x8 f; } u_;                            \
    u_.v[0] = lo_.x; u_.v[1] = lo_.y; u_.v[2] = hi_.x; u_.v[3] = hi_.y; \
    dst = u_.f;                                                   \
  }

  uint4 rg0[3], rg1[3];

  // prologue: issue tiles 0..2, stage x while they fly, write tile 0
  ISSUE(0, rg0[0], rg1[0]);
  ISSUE(1, rg0[1], rg1[1]);
  ISSUE(2, rg0[2], rg1[2]);

  const float* xbase = x + ((size_t)b * N_ + token0) * C_;
  for (int it = 0; it < 12; ++it) {
    int chunk = it * 512 + tid;                // 0..6143
    int row = chunk / 96;
    int col8 = chunk - row * 96;
    const float* p = xbase + (size_t)row * C_ + col8 * 8;
    float4 v0 = *(const float4*)p;
    float4 v1 = *(const float4*)(p + 4);
    bf16x8 tv;
    tv[0] = (__bf16)v0.x; tv[1] = (__bf16)v0.y; tv[2] = (__bf16)v0.z; tv[3] = (__bf16)v0.w;
    tv[4] = (__bf16)v1.x; tv[5] = (__bf16)v1.y; tv[6] = (__bf16)v1.z; tv[7] = (__bf16)v1.w;
    *(bf16x8*)&xs[row][col8 * 8] = tv;
  }
  WTILE(0, rg0[0], rg1[0]);
  __syncthreads();

  f32x4 c2[2][12] = {};   // persistent y accumulator (gate folded into h)

#pragma unroll
  for (int ex = 0; ex < 2; ++ex) {
    const int e = e_idx[ex];
    const float g = gate_v[ex];
    f32x4 c1[2][3] = {};

#pragma unroll
    for (int t = 0; t < 48; ++t) {
      const int s = ex * 48 + t;
      // stage pipeline: loads 3 ahead, write 1 ahead, one barrier
      ISSUE(s + 3, rg0[s % 3], rg1[s % 3]);
      WTILE(s + 1, rg0[(s + 1) % 3], rg1[(s + 1) % 3]);
      __syncthreads();

      const char* buf = stg + (s % 3) * 12288;
      if (t < 24) {
        // ---- G1 step: kb = t. A from xs, B from staged tile.
        bf16x8 a0 = *(const bf16x8*)&xs[arow + ln][t * 32 + q8];
        bf16x8 a1 = *(const bf16x8*)&xs[arow + 16 + ln][t * 32 + q8];
#pragma unroll
        for (int j = 0; j < 3; ++j) {
          bf16x8 bf;
          RFRAG(bf, buf, wn * 48 + j * 16 + ln);
          c1[0][j] = __builtin_amdgcn_mfma_f32_16x16x32_bf16(a0, bf, c1[0][j], 0, 0, 0);
          c1[1][j] = __builtin_amdgcn_mfma_f32_16x16x32_bf16(a1, bf, c1[1][j], 0, 0, 0);
        }
        if (t == 23) {
          // bias + exact gelu + gate scale -> hs (bf16); next step's
          // barrier orders these writes before G2's hs reads.
#pragma unroll
          for (int j = 0; j < 3; ++j) {
            int col = wn * 48 + j * 16 + ln;
            float b1 = fc1_b[e * H_ + col];
#pragma unroll
            for (int m = 0; m < 2; ++m) {
#pragma unroll
              for (int r = 0; r < 4; ++r) {
                int row = arow + m * 16 + q4 + r;
                float v = c1[m][j][r] + b1;
                float gl = 0.5f * v * (1.0f + erff(v * 0.70710678118f));
                hs[row][col] = (__bf16)(g * gl);
              }
            }
          }
        }
      } else {
        // ---- G2 step: slice=(t-24)/6, kb=(t-24)%6. A from hs.
        const int slice = (t - 24) / 6;
        const int kb = (t - 24) % 6;
        bf16x8 a0 = *(const bf16x8*)&hs[arow + ln][kb * 32 + q8];
        bf16x8 a1 = *(const bf16x8*)&hs[arow + 16 + ln][kb * 32 + q8];
#pragma unroll
        for (int j = 0; j < 3; ++j) {
          bf16x8 bf;
          RFRAG(bf, buf, wn * 48 + j * 16 + ln);
          const int cj = slice * 3 + j;
          c2[0][cj] = __builtin_amdgcn_mfma_f32_16x16x32_bf16(a0, bf, c2[0][cj], 0, 0, 0);
          c2[1][cj] = __builtin_amdgcn_mfma_f32_16x16x32_bf16(a1, bf, c2[1][cj], 0, 0, 0);
        }
      }
    }
  }

  // epilogue: out = x + y (+ gate-weighted fc2_b); col = slice*192+wn*48+...
  const float* xr = x + ((size_t)b * N_ + token0) * C_;
  float* outr = out + ((size_t)b * N_ + token0) * C_;
#pragma unroll
  for (int jj = 0; jj < 12; ++jj) {
    int col = (jj / 3) * 192 + wn * 48 + (jj % 3) * 16 + ln;
    float b2t = gate_v[0] * fc2_b[e_idx[0] * C_ + col] +
                gate_v[1] * fc2_b[e_idx[1] * C_ + col];
#pragma unroll
    for (int m = 0; m < 2; ++m) {
#pragma unroll
      for (int r = 0; r < 4; ++r) {
        int row = arow + m * 16 + q4 + r;
        size_t off = (size_t)row * C_ + col;
        outr[off] = xr[off] + c2[m][jj][r] + b2t;
      }
    }
  }
}

// ---------------------------------------------------------------------------
extern "C" void kernel_launch(void* const* d_in, const int* in_sizes, int n_in,
                              void* d_out, int out_size, void* d_ws, size_t ws_size,
                              hipStream_t stream) {
  const float* x      = (const float*)d_in[0];
  const int*   task   = (const int*)d_in[1];
  const float* eps    = (const float*)d_in[2];
  const float* gate_w = (const float*)d_in[3];
  const float* fc1_w  = (const float*)d_in[4];
  const float* fc1_b  = (const float*)d_in[5];
  const float* fc2_w  = (const float*)d_in[6];
  const float* fc2_b  = (const float*)d_in[7];
  float* out = (float*)d_out;

  // workspace: pw1 | pw2 | gwT | psums  (~4.95 MB)
  const size_t nW = (size_t)E_ * H_ * C_;              // 1179648
  __bf16* pw1 = (__bf16*)d_ws;
  __bf16* pw2 = pw1 + nW;
  float* gwT   = (float*)((char*)d_ws + 2 * nW * sizeof(__bf16));
  float* psums = gwT + 4 * 16 * C_;                    // 1024*8 floats

  prep_kernel<<<(nW / 4 + 255) / 256, 256, 0, stream>>>(fc1_w, fc2_w, gate_w,
                                                        pw1, pw2, gwT);
  gate_kernel<<<B_ * 64, 256, 0, stream>>>(x, task, eps, gwT, psums);

  hipFuncSetAttribute(reinterpret_cast<const void*>(expert_kernel),
                      hipFuncAttributeMaxDynamicSharedMemorySize, SMEM_EXPERT);
  expert_kernel<<<B_ * 16, 512, SMEM_EXPERT, stream>>>(
      x, pw1, pw2, fc1_b, fc2_b, psums, out);
}

// Round 10
// 200.349 us; speedup vs baseline: 2.1426x; 2.1426x over previous
//
#include <hip/hip_runtime.h>

#define B_ 16
#define N_ 1024
#define C_ 768
#define E_ 8
#define H_ 192

typedef __bf16 bf16x8 __attribute__((ext_vector_type(8)));
typedef float  f32x4  __attribute__((ext_vector_type(4)));

#define MF16x32 __builtin_amdgcn_mfma_f32_16x16x32_bf16

// ---------------------------------------------------------------------------
// Kernel 1: prep. (a) pack fc1_w/fc2_w to bf16 in MFMA-B-fragment order:
//   pw1[e][kb=c/32][n=h][c%32], pw2[e][kb=h/32][n=c][h%32]
// (b) transpose gate_w to gwT[d][j][c] (f32); rows 0..7 clean, 8..15 noise.
// ---------------------------------------------------------------------------
__global__ __launch_bounds__(256) void prep_kernel(
    const float* __restrict__ w1, const float* __restrict__ w2,
    const float* __restrict__ gw,
    __bf16* __restrict__ pw1, __bf16* __restrict__ pw2,
    float* __restrict__ gwT) {
  int idx = blockIdx.x * 256 + threadIdx.x;            // float4 index
  const int nW4 = (E_ * H_ * C_) / 4;                  // 294912
  if (idx >= nW4) return;
  int flat = idx * 4;
  int e = flat / (H_ * C_);
  int r = flat - e * (H_ * C_);

  // w1: [e][h][c] -> pw1
  {
    float4 a = *(const float4*)(w1 + (size_t)flat);
    int n = r / C_;           // h
    int c = r - n * C_;       // c, %4==0
    size_t o = ((size_t)(e * 24 + (c >> 5)) * 192 + n) * 32 + (c & 31);
    pw1[o + 0] = (__bf16)a.x; pw1[o + 1] = (__bf16)a.y;
    pw1[o + 2] = (__bf16)a.z; pw1[o + 3] = (__bf16)a.w;
  }
  // w2: [e][c][h] -> pw2
  {
    float4 a = *(const float4*)(w2 + (size_t)flat);
    int n = r / H_;           // c index 0..767
    int h = r - n * H_;       // 0..191, %4==0
    size_t o = ((size_t)(e * 6 + (h >> 5)) * 768 + n) * 32 + (h & 31);
    pw2[o + 0] = (__bf16)a.x; pw2[o + 1] = (__bf16)a.y;
    pw2[o + 2] = (__bf16)a.z; pw2[o + 3] = (__bf16)a.w;
  }
  // gwT: [d][c][16] -> [d][j][c]
  if (idx < (4 * 16 * C_) / 4) {
    int f = idx * 4;
    int d = f / (16 * C_);
    int rr = f - d * (16 * C_);
    int j = rr / C_;
    int c = rr - j * C_;      // %4==0
    const float* src = gw + (size_t)d * C_ * 16 + j;
    float4 v;
    v.x = src[(size_t)(c + 0) * 16]; v.y = src[(size_t)(c + 1) * 16];
    v.z = src[(size_t)(c + 2) * 16]; v.w = src[(size_t)(c + 3) * 16];
    *(float4*)(gwT + (size_t)f) = v;
  }
}

// ---------------------------------------------------------------------------
// Kernel 2: gating. Grid = B*64 blocks, 16 tokens each, 256 thr (broadcast
// mapping: 16 lanes share one gwT row -> 4 addrs/wave). Per-block partial
// expert sums -> psums[bid][8].
// ---------------------------------------------------------------------------
__global__ __launch_bounds__(256, 3) void gate_kernel(
    const float* __restrict__ x, const int* __restrict__ task_ids,
    const float* __restrict__ eps, const float* __restrict__ gwT,
    float* __restrict__ psums) {
  const int b = blockIdx.x >> 6;
  const int token0 = (blockIdx.x & 63) * 16;
  const int tid = threadIdx.x;

  __shared__ __align__(16) float xt[16][772];   // pad 4: 2-way (free) reads
  __shared__ float sc[16][16];
  __shared__ float red[16][8];

  const float* xbase = x + ((size_t)b * N_ + token0) * C_;
  for (int it = 0; it < 12; ++it) {
    int chunk = it * 256 + tid;                 // 0..3071
    int row = chunk / 192;
    int col4 = chunk - row * 192;
    float4 v = *(const float4*)(xbase + (size_t)row * C_ + col4 * 4);
    *(float4*)&xt[row][col4 * 4] = v;
  }
  __syncthreads();

  const int t = tid & 15;
  const int j = tid >> 4;                       // 16 lanes share one j
  const int task = task_ids[b];
  const float* wrow = gwT + ((size_t)task * 16 + j) * C_;
  float acc = 0.0f;
#pragma unroll 4
  for (int c = 0; c < C_; c += 4) {
    float4 xv = *(const float4*)&xt[t][c];
    float4 wv = *(const float4*)(wrow + c);
    acc += xv.x * wv.x + xv.y * wv.y + xv.z * wv.z + xv.w * wv.w;
  }
  sc[t][j] = acc;
  __syncthreads();
  if (j < 8) {
    float clean = sc[t][j];
    float raw = sc[t][j + 8];
    float sp = (raw > 20.0f) ? raw : log1pf(expf(raw));
    red[t][j] = clean +
        eps[((size_t)b * N_ + token0 + t) * E_ + j] * (sp + 0.01f);
  }
  __syncthreads();
  if (tid < 8) {
    float s = 0.0f;
#pragma unroll
    for (int tt = 0; tt < 16; ++tt) s += red[tt][tid];
    psums[(size_t)blockIdx.x * 8 + tid] = s;
  }
}

// ---------------------------------------------------------------------------
// Kernel 3: top-2 + 2-expert adapter, LDS-staged weight stream (R9 redo
// with ALL register indices lexically static -- the R9 failure was rule-#20
// scratch spill from rg[s%3] / c2[slice*3+j] dynamic indexing: WRITE_SIZE
// 628 MB of scratch traffic, VGPR 52).
//  - staging regs = 6 named scalars rA0..rC1; steps grouped in 3s so slot
//    indices are literals at every use site (48%3==0, 6%3==0 make the
//    rotation phase structurally constant).
//  - G2 = 4 explicit slices (literal sl) -> c2 indices static.
//  - 16B-XOR swizzle (unit ^= row&3): aligned single ds_read_b128 B-frags,
//    2-way banks (free); conflict-free stores; linear global reads.
//  - per step s: ISSUE(s+3 -> regs slot s%3), STORE(s+1 -> LDS (s+1)%3),
//    barrier, COMPUTE(LDS s%3). Loads ride >=2 compute steps of latency.
// Grid = 256 x 512 thr (8 waves = 2wm x 4wn, M=32/wave), XCD-pinned.
// ---------------------------------------------------------------------------
#define XS_OFF   0                            // bf16 xs[64][776] = 99328
#define HS_OFF   99328                        // bf16 hs[64][200] = 25600
#define STG_OFF  (99328 + 25600)              // 3 x 12288 = 36864
#define SMC_OFF  (STG_OFF + 36864)            // 32
#define SMEM_EXPERT (SMC_OFF + 32)            // 161824 B

#define LOADC(d0, d1, src)                                         \
  { const char* g_ = (const char*)(src);                           \
    d0 = *(const uint4*)(g_ + (size_t)tid * 16);                   \
    if (tid < 256) d1 = *(const uint4*)(g_ + 8192 + (size_t)tid * 16); }

#define STORE_TILE(slot, d0, d1)                                   \
  { char* buf_ = stg + (slot) * 12288;                             \
    { int r_ = tid >> 2, p_ = tid & 3;                             \
      *(uint4*)(buf_ + r_ * 64 + ((p_ ^ (r_ & 3)) * 16)) = d0; }   \
    if (tid < 256) {                                               \
      int c_ = 512 + tid; int r_ = c_ >> 2, p_ = c_ & 3;           \
      *(uint4*)(buf_ + r_ * 64 + ((p_ ^ (r_ & 3)) * 16)) = d1; } }

#define RFRAG(dst, slot, n)                                        \
  { int n_ = (n);                                                  \
    dst = *(const bf16x8*)(stg + (slot) * 12288 + n_ * 64          \
                           + ((qq ^ (n_ & 3)) * 16)); }

// step s: prefetch (cond) into regs R[s%3]; store R[(s+1)%3] -> LDS slot
// (s+1)%3 (cond); barrier. All conds block-uniform.
#define PIPE_STEP(PFC, PFA, RC0, RC1, RN0, RN1, SLN, STC)          \
  { if (PFC) { LOADC(RC0, RC1, PFA); }                             \
    if (STC) { STORE_TILE(SLN, RN0, RN1); }                        \
    __syncthreads(); }

#define G1_COMPUTE(t_, sk)                                               \
  { bf16x8 a0 = *(const bf16x8*)&xs[arow + ln][(t_) * 32 + q8];          \
    bf16x8 a1 = *(const bf16x8*)&xs[arow + 16 + ln][(t_) * 32 + q8];     \
    bf16x8 b0, b1, b2;                                                   \
    RFRAG(b0, sk, wn * 48 + ln);                                         \
    RFRAG(b1, sk, wn * 48 + 16 + ln);                                    \
    RFRAG(b2, sk, wn * 48 + 32 + ln);                                    \
    c1[0][0] = MF16x32(a0, b0, c1[0][0], 0, 0, 0);                       \
    c1[1][0] = MF16x32(a1, b0, c1[1][0], 0, 0, 0);                       \
    c1[0][1] = MF16x32(a0, b1, c1[0][1], 0, 0, 0);                       \
    c1[1][1] = MF16x32(a1, b1, c1[1][1], 0, 0, 0);                       \
    c1[0][2] = MF16x32(a0, b2, c1[0][2], 0, 0, 0);                       \
    c1[1][2] = MF16x32(a1, b2, c1[1][2], 0, 0, 0); }

#define G2_COMPUTE(kb_, sk, sl_)                                         \
  { bf16x8 a0 = *(const bf16x8*)&hs[arow + ln][(kb_) * 32 + q8];         \
    bf16x8 a1 = *(const bf16x8*)&hs[arow + 16 + ln][(kb_) * 32 + q8];    \
    bf16x8 b0, b1, b2;                                                   \
    RFRAG(b0, sk, wn * 48 + ln);                                         \
    RFRAG(b1, sk, wn * 48 + 16 + ln);                                    \
    RFRAG(b2, sk, wn * 48 + 32 + ln);                                    \
    c2[0][(sl_)*3+0] = MF16x32(a0, b0, c2[0][(sl_)*3+0], 0, 0, 0);       \
    c2[1][(sl_)*3+0] = MF16x32(a1, b0, c2[1][(sl_)*3+0], 0, 0, 0);       \
    c2[0][(sl_)*3+1] = MF16x32(a0, b1, c2[0][(sl_)*3+1], 0, 0, 0);       \
    c2[1][(sl_)*3+1] = MF16x32(a1, b1, c2[1][(sl_)*3+1], 0, 0, 0);       \
    c2[0][(sl_)*3+2] = MF16x32(a0, b2, c2[0][(sl_)*3+2], 0, 0, 0);       \
    c2[1][(sl_)*3+2] = MF16x32(a1, b2, c2[1][(sl_)*3+2], 0, 0, 0); }

__global__ __launch_bounds__(512, 2) void expert_kernel(
    const float* __restrict__ x, const __bf16* __restrict__ pw1,
    const __bf16* __restrict__ pw2, const float* __restrict__ fc1_b,
    const float* __restrict__ fc2_b, const float* __restrict__ psums,
    float* __restrict__ out) {
  const int bid = blockIdx.x;
  const int sxc = bid >> 3;                    // 0..31 within an XCD
  const int b = (bid & 7) * 2 + (sxc >> 4);    // 2 consecutive samples / XCD
  const int token0 = (sxc & 15) * 64;
  const int tid = threadIdx.x;
  const int wave = tid >> 6;
  const int wm = wave >> 2;                    // token half (0/1)
  const int wn = wave & 3;                     // N slice (0..3)
  const int lane = tid & 63;
  const int ln = lane & 15;
  const int qq = lane >> 4;                    // 0..3
  const int q8 = qq * 8;
  const int q4 = qq * 4;
  const int arow = wm * 32;

  extern __shared__ char smem[];
  __bf16 (*xs)[776] = reinterpret_cast<__bf16(*)[776]>(smem + XS_OFF);
  __bf16 (*hs)[200] = reinterpret_cast<__bf16(*)[200]>(smem + HS_OFF);
  char* stg = smem + STG_OFF;
  float* smc = reinterpret_cast<float*>(smem + SMC_OFF);

  // ---- per-sample gate sums: wave e reduces 64 tile-partials --------------
  {
    float v = psums[(((size_t)b << 6) | lane) * 8 + wave];
#pragma unroll
    for (int off = 32; off; off >>= 1) v += __shfl_down(v, off);
    if (lane == 0) smc[wave] = v;
  }
  __syncthreads();

  // top-2 (tie rule matches lax.top_k: strict >, stable)
  int e_idx[2]; float gate_v[2];
  {
    float best = -INFINITY, best2 = -INFINITY;
    int i1 = 0, i2 = 0;
#pragma unroll
    for (int e = 0; e < E_; ++e) {
      float v = smc[e];
      if (v > best) { best2 = best; i2 = i1; best = v; i1 = e; }
      else if (v > best2) { best2 = v; i2 = e; }
    }
    float d = best - best2;
    float st = d / (d + 1e-6f);
    float et = expf(st);
    e_idx[0] = i1; gate_v[0] = et / (et + 1.0f);
    e_idx[1] = i2; gate_v[1] = 1.0f / (et + 1.0f);
  }

  uint4 rA0, rA1, rB0, rB1, rC0, rC1;          // named staging regs (no arrays)

  // prologue: issue expert-0 G1 tiles 0..2; stage x while they fly;
  // store tile 0 into LDS slot 0; barrier.
  {
    const char* w10 = (const char*)pw1 + (size_t)e_idx[0] * 294912;
    LOADC(rA0, rA1, w10);
    LOADC(rB0, rB1, w10 + 12288);
    LOADC(rC0, rC1, w10 + 24576);
  }
  const float* xbase = x + ((size_t)b * N_ + token0) * C_;
  for (int it = 0; it < 12; ++it) {
    int chunk = it * 512 + tid;                // 0..6143
    int row = chunk / 96;
    int col8 = chunk - row * 96;
    const float* p = xbase + (size_t)row * C_ + col8 * 8;
    float4 v0 = *(const float4*)p;
    float4 v1 = *(const float4*)(p + 4);
    bf16x8 tv;
    tv[0] = (__bf16)v0.x; tv[1] = (__bf16)v0.y; tv[2] = (__bf16)v0.z; tv[3] = (__bf16)v0.w;
    tv[4] = (__bf16)v1.x; tv[5] = (__bf16)v1.y; tv[6] = (__bf16)v1.z; tv[7] = (__bf16)v1.w;
    *(bf16x8*)&xs[row][col8 * 8] = tv;
  }
  STORE_TILE(0, rA0, rA1);
  __syncthreads();

  f32x4 c2[2][12] = {};   // persistent y accumulator (gate folded into h)

  for (int ex = 0; ex < 2; ++ex) {             // runtime loop: all reg idx static
    const int e = ex ? e_idx[1] : e_idx[0];
    const float g = ex ? gate_v[1] : gate_v[0];
    const char* cw1 = (const char*)pw1 + (size_t)e * 294912;
    const char* cw2 = (const char*)pw2 + (size_t)e * 294912;
    const char* nw1 = (const char*)pw1 + (size_t)e_idx[1] * 294912; // ex==0 only
    f32x4 c1[2][3] = {};

    // ---- G1 steps t=0..20 (7 groups of 3; slot(t)=t%3 static per line) ----
#pragma unroll
    for (int g3 = 0; g3 < 7; ++g3) {
      const int t0 = g3 * 3;
      PIPE_STEP(1, cw1 + (size_t)(t0 + 3) * 12288, rA0, rA1, rB0, rB1, 1, 1);
      G1_COMPUTE(t0, 0);
      PIPE_STEP(1, cw1 + (size_t)(t0 + 4) * 12288, rB0, rB1, rC0, rC1, 2, 1);
      G1_COMPUTE(t0 + 1, 1);
      PIPE_STEP(1, cw1 + (size_t)(t0 + 5) * 12288, rC0, rC1, rA0, rA1, 0, 1);
      G1_COMPUTE(t0 + 2, 2);
    }
    // ---- G1 tail t=21..23: prefetch targets are G2 slice-0 tiles ----------
    PIPE_STEP(1, cw2,             rA0, rA1, rB0, rB1, 1, 1); G1_COMPUTE(21, 0);
    PIPE_STEP(1, cw2 + 49152,     rB0, rB1, rC0, rC1, 2, 1); G1_COMPUTE(22, 1);
    PIPE_STEP(1, cw2 + 2 * 49152, rC0, rC1, rA0, rA1, 0, 1); G1_COMPUTE(23, 2);

    // bias + exact gelu + gate scale -> hs (bf16); next barrier orders
    // these writes before G2's hs reads.
#pragma unroll
    for (int j = 0; j < 3; ++j) {
      int col = wn * 48 + j * 16 + ln;
      float b1 = fc1_b[e * H_ + col];
#pragma unroll
      for (int m = 0; m < 2; ++m) {
#pragma unroll
        for (int r = 0; r < 4; ++r) {
          int row = arow + m * 16 + q4 + r;
          float v = c1[m][j][r] + b1;
          float gl = 0.5f * v * (1.0f + erff(v * 0.70710678118f));
          hs[row][col] = (__bf16)(g * gl);
        }
      }
    }

    // ---- G2: 4 explicit slices x 6 kb steps; slot(kb)=kb%3 static ---------
    // tile(sl,kb) at cw2 + kb*49152 + sl*12288. Prefetch +3 steps.
#define G2_SLICE(sl_)                                                        \
    PIPE_STEP(1, cw2 + (size_t)3 * 49152 + (sl_) * 12288,                    \
              rA0, rA1, rB0, rB1, 1, 1);                                     \
    G2_COMPUTE(0, 0, sl_);                                                   \
    PIPE_STEP(1, cw2 + (size_t)4 * 49152 + (sl_) * 12288,                    \
              rB0, rB1, rC0, rC1, 2, 1);                                     \
    G2_COMPUTE(1, 1, sl_);                                                   \
    PIPE_STEP(1, cw2 + (size_t)5 * 49152 + (sl_) * 12288,                    \
              rC0, rC1, rA0, rA1, 0, 1);                                     \
    G2_COMPUTE(2, 2, sl_);                                                   \
    PIPE_STEP(1, cw2 + ((sl_) + 1) * 12288, rA0, rA1, rB0, rB1, 1, 1);       \
    G2_COMPUTE(3, 0, sl_);                                                   \
    PIPE_STEP(1, cw2 + (size_t)49152 + ((sl_) + 1) * 12288,                  \
              rB0, rB1, rC0, rC1, 2, 1);                                     \
    G2_COMPUTE(4, 1, sl_);                                                   \
    PIPE_STEP(1, cw2 + (size_t)2 * 49152 + ((sl_) + 1) * 12288,              \
              rC0, rC1, rA0, rA1, 0, 1);                                     \
    G2_COMPUTE(5, 2, sl_);

    G2_SLICE(0)
    G2_SLICE(1)
    G2_SLICE(2)
    // slice 3: kb 0..2 prefetch this expert's last tiles; kb 3..5 prefetch
    // next expert's G1 tiles 0..2 (ex==0 only); final store skipped at ex==1.
    PIPE_STEP(1, cw2 + (size_t)3 * 49152 + 3 * 12288, rA0, rA1, rB0, rB1, 1, 1);
    G2_COMPUTE(0, 0, 3);
    PIPE_STEP(1, cw2 + (size_t)4 * 49152 + 3 * 12288, rB0, rB1, rC0, rC1, 2, 1);
    G2_COMPUTE(1, 1, 3);
    PIPE_STEP(1, cw2 + (size_t)5 * 49152 + 3 * 12288, rC0, rC1, rA0, rA1, 0, 1);
    G2_COMPUTE(2, 2, 3);
    PIPE_STEP(ex == 0, nw1,             rA0, rA1, rB0, rB1, 1, 1);
    G2_COMPUTE(3, 0, 3);
    PIPE_STEP(ex == 0, nw1 + 12288,     rB0, rB1, rC0, rC1, 2, 1);
    G2_COMPUTE(4, 1, 3);
    PIPE_STEP(ex == 0, nw1 + 24576,     rC0, rC1, rA0, rA1, 0, ex == 0);
    G2_COMPUTE(5, 2, 3);
#undef G2_SLICE
  }

  // epilogue: out = x + y (+ gate-weighted fc2_b); col = slice*192+wn*48+...
  const float* xr = x + ((size_t)b * N_ + token0) * C_;
  float* outr = out + ((size_t)b * N_ + token0) * C_;
#pragma unroll
  for (int jj = 0; jj < 12; ++jj) {
    int col = (jj / 3) * 192 + wn * 48 + (jj % 3) * 16 + ln;
    float b2t = gate_v[0] * fc2_b[e_idx[0] * C_ + col] +
                gate_v[1] * fc2_b[e_idx[1] * C_ + col];
#pragma unroll
    for (int m = 0; m < 2; ++m) {
#pragma unroll
      for (int r = 0; r < 4; ++r) {
        int row = arow + m * 16 + q4 + r;
        size_t off = (size_t)row * C_ + col;
        outr[off] = xr[off] + c2[m][jj][r] + b2t;
      }
    }
  }
}

// ---------------------------------------------------------------------------
extern "C" void kernel_launch(void* const* d_in, const int* in_sizes, int n_in,
                              void* d_out, int out_size, void* d_ws, size_t ws_size,
                              hipStream_t stream) {
  const float* x      = (const float*)d_in[0];
  const int*   task   = (const int*)d_in[1];
  const float* eps    = (const float*)d_in[2];
  const float* gate_w = (const float*)d_in[3];
  const float* fc1_w  = (const float*)d_in[4];
  const float* fc1_b  = (const float*)d_in[5];
  const float* fc2_w  = (const float*)d_in[6];
  const float* fc2_b  = (const float*)d_in[7];
  float* out = (float*)d_out;

  // workspace: pw1 | pw2 | gwT | psums  (~4.95 MB)
  const size_t nW = (size_t)E_ * H_ * C_;              // 1179648
  __bf16* pw1 = (__bf16*)d_ws;
  __bf16* pw2 = pw1 + nW;
  float* gwT   = (float*)((char*)d_ws + 2 * nW * sizeof(__bf16));
  float* psums = gwT + 4 * 16 * C_;                    // 1024*8 floats

  prep_kernel<<<(nW / 4 + 255) / 256, 256, 0, stream>>>(fc1_w, fc2_w, gate_w,
                                                        pw1, pw2, gwT);
  gate_kernel<<<B_ * 64, 256, 0, stream>>>(x, task, eps, gwT, psums);

  hipFuncSetAttribute(reinterpret_cast<const void*>(expert_kernel),
                      hipFuncAttributeMaxDynamicSharedMemorySize, SMEM_EXPERT);
  expert_kernel<<<B_ * 16, 512, SMEM_EXPERT, stream>>>(
      x, pw1, pw2, fc1_b, fc2_b, psums, out);
}